// Round 10
// baseline (386.145 us; speedup 1.0000x reference)
//
#include <hip/hip_runtime.h>

// Problem: B=512, T=256, C=384, HS=64.  out = softmax(tril(tanh(x@Ws))) @ (x@Wv)
// with Ws = Wq@Wql + Wk@Wkl  (elementwise add of q_w,k_w collapses: both linear in x).
// Lineage: composition of two HW-verified kernels:
//   - R3's barrier-free K-loop (X and W both global->regs per wave; correctness PASSED
//     on hardware; its 420us came from unroll-spill, not the design), plus
//   - R9's register discipline (kc loop ROLLED: #pragma unroll 1 — R9 proved rolled
//     => VGPR 108 / WRITE 33MB vs unrolled => ~230 regs + 700-800MB scratch spill).
// K-loop has ZERO __syncthreads: each of the 8 waves streams its own X rows (HBM)
// and its own W fragments (L2-resident 240KB blob, ~810MB aggregate L2 traffic
// ~= 23us at 34.5TB/s) into registers => 8 independent pipelines per CU instead of
// lock-step LDS producer-consumer staging (R0/R1/R9 all stall ~20-27K cyc/kc with
// MfmaUtil 7% / VALU 15% / HBM 12% regardless of barrier count).
// Epilogue/phase-2 byte-identical to the verified lineage at R3's LDS offsets.
#define BATCH 512
#define TT    256
#define CC    384
#define HH    64

typedef float  f32x4 __attribute__((ext_vector_type(4)));
typedef short  s16x8 __attribute__((ext_vector_type(8)));

// LDS: only Vb (block-shared V, B-frag order) + per-wave transpose scratch.
#define VB_OFF   0        // [vct4][ch8][lane64][8] bf16 = 32768
#define SCR_OFF  32768    // 8 waves x 1024B
#define LDS_TOTAL 40960

__device__ __forceinline__ unsigned short f2bf(float f) {
    union { float f; unsigned u; } c; c.f = f;
    unsigned u = c.u;
    u += 0x7fffu + ((u >> 16) & 1u);   // RNE
    return (unsigned short)(u >> 16);
}

// ---------------- Kernel A: build bf16 weight blob in ws ----------------
// Blob: [kc6][kk2][ct20][lane64][j8] bf16.  Element (k in [0,384), n in [0,320)):
//   kc=k>>6, kk=(k>>5)&1, ct=n>>4, lane=((k>>3)&3)*16 + (n&15), j=k&7.
// ct 0..15 = Ws^T (B-frag), ct 16..19 = Wv^T.
__global__ void prep_w(const float* __restrict__ Wq, const float* __restrict__ Wk,
                       const float* __restrict__ Wv, const float* __restrict__ Wql,
                       const float* __restrict__ Wkl, unsigned short* __restrict__ wsW) {
    int gid = blockIdx.x * 256 + threadIdx.x;   // covers 384*256 + 384*64 = 122880
    int k, n; float val;
    if (gid < CC * 256) {
        k = gid >> 8; int s = gid & 255; n = s;
        float acc = 0.f;
        for (int h = 0; h < HH; ++h)
            acc += Wq[k * HH + h] * Wql[h * 256 + s] + Wk[k * HH + h] * Wkl[h * 256 + s];
        val = acc;
    } else {
        int g2 = gid - CC * 256;
        k = g2 >> 6; int h = g2 & 63; n = 256 + h;
        val = Wv[k * HH + h];
    }
    int kc = k >> 6, kk = (k >> 5) & 1, ct = n >> 4;
    int lane = ((k >> 3) & 3) * 16 + (n & 15);
    int j = k & 7;
    wsW[((((kc * 2 + kk) * 20 + ct) * 64) + lane) * 8 + j] = f2bf(val);
}

// ---------------- Kernel B: per-batch fused attention, BARRIER-FREE K-loop ----------------
__global__ __launch_bounds__(512, 2) void head_main(const float* __restrict__ x,
                                                    const unsigned short* __restrict__ wsW,
                                                    float* __restrict__ out) {
    extern __shared__ char sm[];
    unsigned short* Vb = (unsigned short*)(sm + VB_OFF);

    const int b    = blockIdx.x;
    const int t    = threadIdx.x;
    const int w    = (t >> 6) & 7;      // wave 0..7
    const int lane = t & 63;
    const int q    = lane >> 4;
    const int cidx = lane & 15;
    const int rt0  = w;                 // <= 7
    const int rt1  = 15 - w;            // >= 8
    unsigned short* scr = (unsigned short*)(sm + SCR_OFF) + w * 512;  // 1KB/wave

    const float* xb = x + (size_t)b * (TT * CC);

    // Per-lane A-frag base: frag(rt,kk,kc) element j is
    //   x[rt*16 + (lane&15)][kc*64 + kk*32 + (lane>>4)*8 + j]   (8 floats = 2 float4)
    const float* xa0 = xb + (rt0 * 16 + cidx) * CC + q * 8;
    const float* xa1 = xb + (rt1 * 16 + cidx) * CC + q * 8;
    // Per-lane W-frag base: frag(kc,kk,ct) = wsW[(((kc*2+kk)*20+ct)*64 + lane)*8 ..+8]
    const unsigned short* wlane = wsW + lane * 8;

    // Accumulators: wave owns row-tiles rt0,rt1 across ALL col-tiles (causal-trimmed).
    f32x4 accS0[8], accS1[16], accV[2][4];
#pragma unroll
    for (int i = 0; i < 8; ++i)  accS0[i] = (f32x4){0.f,0.f,0.f,0.f};
#pragma unroll
    for (int i = 0; i < 16; ++i) accS1[i] = (f32x4){0.f,0.f,0.f,0.f};
#pragma unroll
    for (int i = 0; i < 2; ++i)
#pragma unroll
        for (int j = 0; j < 4; ++j) accV[i][j] = (f32x4){0.f,0.f,0.f,0.f};

    auto pack8 = [&](const float4& f0, const float4& f1) -> s16x8 {
        s16x8 v;
        v[0] = (short)f2bf(f0.x); v[1] = (short)f2bf(f0.y);
        v[2] = (short)f2bf(f0.z); v[3] = (short)f2bf(f0.w);
        v[4] = (short)f2bf(f1.x); v[5] = (short)f2bf(f1.y);
        v[6] = (short)f2bf(f1.z); v[7] = (short)f2bf(f1.w);
        return v;
    };

    // ---- K-loop: 6 iterations of BK=64.  ROLLED (unroll-spill guard, R9 evidence);
    // no __syncthreads, no LDS — per-wave register streaming only.
#pragma unroll 1
    for (int kc = 0; kc < 6; ++kc) {
        // X frags for this wave's two rows (issue first: longest latency)
        const float* p0 = xa0 + kc * 64;
        const float* p1 = xa1 + kc * 64;
        float4 x00 = *(const float4*)(p0);
        float4 x01 = *(const float4*)(p0 + 4);
        float4 x02 = *(const float4*)(p0 + 32);
        float4 x03 = *(const float4*)(p0 + 36);
        float4 x10 = *(const float4*)(p1);
        float4 x11 = *(const float4*)(p1 + 4);
        float4 x12 = *(const float4*)(p1 + 32);
        float4 x13 = *(const float4*)(p1 + 36);
        s16x8 a00 = pack8(x00, x01);   // rt0, kk=0
        s16x8 a01 = pack8(x02, x03);   // rt0, kk=1
        s16x8 a10 = pack8(x10, x11);   // rt1, kk=0
        s16x8 a11 = pack8(x12, x13);   // rt1, kk=1

        const unsigned short* wkc = wlane + (size_t)(kc * 2) * (20 * 512);
#pragma unroll
        for (int kk = 0; kk < 2; ++kk) {
            s16x8 a0 = kk ? a01 : a00;
            s16x8 a1 = kk ? a11 : a10;
            const unsigned short* wb = wkc + kk * (20 * 512);
#pragma unroll
            for (int ct = 0; ct < 16; ++ct) {
                if (ct <= rt1) {           // rt1 >= 8: folds true for ct<=8
                    s16x8 bf = *(const s16x8*)(wb + ct * 512);
                    accS1[ct] = __builtin_amdgcn_mfma_f32_16x16x32_bf16(a1, bf, accS1[ct], 0, 0, 0);
                    if (ct < 8 && ct <= rt0)
                        accS0[ct] = __builtin_amdgcn_mfma_f32_16x16x32_bf16(a0, bf, accS0[ct], 0, 0, 0);
                }
            }
#pragma unroll
            for (int v2 = 0; v2 < 4; ++v2) {
                s16x8 bf = *(const s16x8*)(wb + (16 + v2) * 512);
                accV[0][v2] = __builtin_amdgcn_mfma_f32_16x16x32_bf16(a0, bf, accV[0][v2], 0, 0, 0);
                accV[1][v2] = __builtin_amdgcn_mfma_f32_16x16x32_bf16(a1, bf, accV[1][v2], 0, 0, 0);
            }
        }
    }

    // ---- epilogue: E = exp(tanh(S)) masked -> A-frags (via per-wave scratch), V -> Vb, rowsums ----
    float rs0[4] = {0.f,0.f,0.f,0.f}, rs1[4] = {0.f,0.f,0.f,0.f};
    s16x8 pf0[4], pf1[8];

#pragma unroll
    for (int ch = 0; ch < 8; ++ch) {
        if (ch <= (rt1 >> 1)) {
#pragma unroll
            for (int sub = 0; sub < 2; ++sub) {
                const int ct = 2 * ch + sub;
                const int gcol = ct * 16 + cidx;
                const int c = sub * 16 + cidx;
#pragma unroll
                for (int rg = 0; rg < 4; ++rg) {
                    const int grow = rt1 * 16 + q * 4 + rg;
                    float e = 0.f;
                    if (ct <= rt1 && gcol <= grow) {
                        float sv = accS1[2 * ch + sub][rg];
                        float ex = __expf(2.f * sv);
                        float th = 1.f - __fdividef(2.f, ex + 1.f);   // tanh
                        e = __expf(th);                                // bounded -> no max-sub needed
                    }
                    rs1[rg] += e;
                    scr[((c >> 3) * 16 + q * 4 + rg) * 8 + (c & 7)] = f2bf(e);
                }
            }
            pf1[ch] = *(const s16x8*)(scr + lane * 8);   // in-wave DS ordered
        }
    }
#pragma unroll
    for (int ch = 0; ch < 4; ++ch) {
        if (ch <= (rt0 >> 1)) {
#pragma unroll
            for (int sub = 0; sub < 2; ++sub) {
                const int ct = 2 * ch + sub;
                const int gcol = ct * 16 + cidx;
                const int c = sub * 16 + cidx;
#pragma unroll
                for (int rg = 0; rg < 4; ++rg) {
                    const int grow = rt0 * 16 + q * 4 + rg;
                    float e = 0.f;
                    if (ct <= rt0 && gcol <= grow) {
                        float sv = accS0[2 * ch + sub][rg];
                        float ex = __expf(2.f * sv);
                        float th = 1.f - __fdividef(2.f, ex + 1.f);
                        e = __expf(th);
                    }
                    rs0[rg] += e;
                    scr[((c >> 3) * 16 + q * 4 + rg) * 8 + (c & 7)] = f2bf(e);
                }
            }
            pf0[ch] = *(const s16x8*)(scr + lane * 8);
        }
    }

    // V -> Vb (B-frag order for PV)
#pragma unroll
    for (int ri = 0; ri < 2; ++ri) {
        const int rt = ri ? rt1 : rt0;
#pragma unroll
        for (int vct = 0; vct < 4; ++vct)
#pragma unroll
            for (int rg = 0; rg < 4; ++rg) {
                int srow = rt * 16 + q * 4 + rg;
                Vb[((vct * 8 + (srow >> 5)) * 64 + ((srow >> 3) & 3) * 16 + cidx) * 8 + (srow & 7)] =
                    f2bf(accV[ri][vct][rg]);
            }
    }

    // rowsums: reduce across the 16 lanes sharing each row (quad-group), replicated
#pragma unroll
    for (int rg = 0; rg < 4; ++rg) {
        float v0 = rs0[rg], v1 = rs1[rg];
        v0 += __shfl_xor(v0, 1); v0 += __shfl_xor(v0, 2);
        v0 += __shfl_xor(v0, 4); v0 += __shfl_xor(v0, 8);
        v1 += __shfl_xor(v1, 1); v1 += __shfl_xor(v1, 2);
        v1 += __shfl_xor(v1, 4); v1 += __shfl_xor(v1, 8);
        rs0[rg] = v0; rs1[rg] = v1;
    }

    __syncthreads();   // Vb visible to all waves (the ONLY barrier)

    // ---- phase 2: out = (E @ V) / rowsum — fully per-wave ----
    f32x4 acc2[2][4];
#pragma unroll
    for (int i = 0; i < 2; ++i)
#pragma unroll
        for (int j = 0; j < 4; ++j) acc2[i][j] = (f32x4){0.f,0.f,0.f,0.f};

    const int nch0 = rt0 >> 1, nch1 = rt1 >> 1;
#pragma unroll
    for (int ch = 0; ch < 8; ++ch) {
        if (ch <= nch1) {
            s16x8 vb[4];
#pragma unroll
            for (int vct = 0; vct < 4; ++vct)
                vb[vct] = *(const s16x8*)(Vb + ((vct * 8 + ch) * 64 + lane) * 8);
#pragma unroll
            for (int vct = 0; vct < 4; ++vct)
                acc2[1][vct] = __builtin_amdgcn_mfma_f32_16x16x32_bf16(pf1[ch], vb[vct], acc2[1][vct], 0, 0, 0);
            if (ch < 4 && ch <= nch0) {
#pragma unroll
                for (int vct = 0; vct < 4; ++vct)
                    acc2[0][vct] = __builtin_amdgcn_mfma_f32_16x16x32_bf16(pf0[ch], vb[vct], acc2[0][vct], 0, 0, 0);
            }
        }
    }

    float* ob = out + (size_t)b * (TT * HH);
#pragma unroll
    for (int ri = 0; ri < 2; ++ri) {
        const int rt = ri ? rt1 : rt0;
#pragma unroll
        for (int rg = 0; rg < 4; ++rg) {
            int row = rt * 16 + q * 4 + rg;
            float inv = __fdividef(1.f, ri ? rs1[rg] : rs0[rg]);
#pragma unroll
            for (int vct = 0; vct < 4; ++vct)
                ob[row * HH + vct * 16 + cidx] = acc2[ri][vct][rg] * inv;
        }
    }
}

extern "C" void kernel_launch(void* const* d_in, const int* in_sizes, int n_in,
                              void* d_out, int out_size, void* d_ws, size_t ws_size,
                              hipStream_t stream) {
    const float* x   = (const float*)d_in[0];
    const float* Wq  = (const float*)d_in[1];
    const float* Wk  = (const float*)d_in[2];
    const float* Wv  = (const float*)d_in[3];
    const float* Wql = (const float*)d_in[4];
    const float* Wkl = (const float*)d_in[5];
    unsigned short* wsW = (unsigned short*)d_ws;   // 245760 B blob
    float* out = (float*)d_out;

    prep_w<<<480, 256, 0, stream>>>(Wq, Wk, Wv, Wql, Wkl, wsW);

    head_main<<<BATCH, 512, LDS_TOTAL, stream>>>(x, wsW, out);
}